// Round 7
// baseline (409.573 us; speedup 1.0000x reference)
//
#include <hip/hip_runtime.h>
#include <cstdint>
#include <cmath>

#define DIM   768
#define HID   3072
#define NEXP  8
#define DLOW  192
#define NPB   1024            // tokens per image (32*32)
#define NTOK  8192
#define KD    1536            // NEXP*DLOW
#define KCAT  4608            // HID + KD

typedef unsigned short ushort_t;
typedef short   short8  __attribute__((ext_vector_type(8)));
typedef float   float4v __attribute__((ext_vector_type(4)));

__device__ inline ushort_t f2b(float f) {
    union { float f; unsigned int i; } v; v.f = f;
    unsigned int x = v.i;
    return (ushort_t)((x + 0x7fffu + ((x >> 16) & 1u)) >> 16);   // RNE
}
__device__ inline float b2f(ushort_t u) {
    union { unsigned int i; float f; } v; v.i = ((unsigned int)u) << 16; return v.f;
}
__device__ inline float gelu_exact(float v) {
    return 0.5f * v * (1.0f + erff(v * 0.70710678118654752440f));
}

// async global->LDS, 16 B per lane (global_load_lds_dwordx4)
__device__ __forceinline__ void async_ld16(const ushort_t* g, ushort_t* l) {
    __builtin_amdgcn_global_load_lds(
        (const __attribute__((address_space(1))) void*)g,
        (__attribute__((address_space(3))) void*)l,
        16, 0, 0);
}

// ===========================================================================
// Shared BK=64 XOR-swizzled MFMA core (0 LDS bank conflicts, r5/r6-proven).
// Computes acc[4][4] (128x128 tile, 4 waves) of A[m,:].B[n,:] over k in
// [kb,ke). A,B row stride = K elems.
// ===========================================================================
#define GEMM_CORE(A, B, K, kb, ke)                                            \
    const int tid  = threadIdx.x;                                             \
    const int lane = tid & 63;                                                \
    const int wave = tid >> 6;                                                \
    const int quad = lane >> 4;                                               \
    const int l16  = lane & 15;                                               \
    const int wm   = (wave >> 1) * 64;                                        \
    const int wn   = (wave & 1) * 64;                                         \
    const int m0   = blockIdx.y * 128;                                        \
    const int n0   = blockIdx.x * 128;                                        \
    float4v acc[4][4];                                                        \
    _Pragma("unroll")                                                         \
    for (int i = 0; i < 4; i++)                                               \
        _Pragma("unroll")                                                     \
        for (int j = 0; j < 4; j++) acc[i][j] = (float4v)0.0f;                \
    const ushort_t* ga[4]; const ushort_t* gb[4];                             \
    ushort_t* la[4]; ushort_t* lb[4];                                         \
    _Pragma("unroll")                                                         \
    for (int j = 0; j < 4; j++) {                                             \
        const int f = j * 256 + tid;                                          \
        const int mm = f >> 3;                                                \
        const int gs = ((f & 7) ^ (mm & 7)) * 8;                              \
        ga[j] = A + (size_t)(m0 + mm) * K + gs;                               \
        gb[j] = B + (size_t)(n0 + mm) * K + gs;                               \
        la[j] = &As[f * 8];                                                   \
        lb[j] = &Bs[f * 8];                                                   \
    }                                                                         \
    const ushort_t* pa[2][4]; const ushort_t* pb[2][4];                       \
    _Pragma("unroll")                                                         \
    for (int kh = 0; kh < 2; kh++)                                            \
        _Pragma("unroll")                                                     \
        for (int i = 0; i < 4; i++) {                                         \
            const int ra = wm + i * 16 + l16;                                 \
            pa[kh][i] = &As[ra * 64 + (((quad + 4 * kh) ^ (ra & 7)) * 8)];    \
            const int rb = wn + i * 16 + l16;                                 \
            pb[kh][i] = &Bs[rb * 64 + (((quad + 4 * kh) ^ (rb & 7)) * 8)];    \
        }                                                                     \
    for (int k0 = (kb); k0 < (ke); k0 += 64) {                                \
        __syncthreads();                                                      \
        _Pragma("unroll")                                                     \
        for (int j = 0; j < 4; j++) async_ld16(ga[j] + k0, la[j]);            \
        _Pragma("unroll")                                                     \
        for (int j = 0; j < 4; j++) async_ld16(gb[j] + k0, lb[j]);            \
        __syncthreads();                                                      \
        _Pragma("unroll")                                                     \
        for (int kh = 0; kh < 2; kh++) {                                      \
            short8 af[4], bv[4];                                              \
            _Pragma("unroll")                                                 \
            for (int i = 0; i < 4; i++) af[i] = *(const short8*)pa[kh][i];    \
            _Pragma("unroll")                                                 \
            for (int i = 0; i < 4; i++) bv[i] = *(const short8*)pb[kh][i];    \
            _Pragma("unroll")                                                 \
            for (int im = 0; im < 4; im++)                                    \
                _Pragma("unroll")                                             \
                for (int in = 0; in < 4; in++)                                \
                    acc[im][in] = __builtin_amdgcn_mfma_f32_16x16x32_bf16(    \
                        af[im], bv[in], acc[im][in], 0, 0, 0);                \
        }                                                                     \
    }

// ---------------------------------------------------------------------------
// INPUT GEMM: HU[m, col] = XT[m,:].Win[col,:]  (K=768), fused epilogue:
//   col <  HID : bf16(gelu(acc + b1[col]))
//   col >= HID : bf16(gelu(acc) * routing_weight(token, expert(col)))
// Also: block (0,0) of chunk 0 writes the aux-loss scalar.
// ---------------------------------------------------------------------------
__global__ __launch_bounds__(256)
void gemm_in(const ushort_t* __restrict__ A, const ushort_t* __restrict__ B,
             ushort_t* __restrict__ Cb, const float* __restrict__ bias,
             const int* __restrict__ tokE, const float* __restrict__ tokW,
             const float* __restrict__ accbuf, float* __restrict__ outAux,
             int m_base)
{
    __shared__ __align__(16) ushort_t As[128 * 64];
    __shared__ __align__(16) ushort_t Bs[128 * 64];
    GEMM_CORE(A, B, DIM, 0, DIM)

    if (n0 < HID) {                        // shared-expert hidden: gelu + b1
#pragma unroll
        for (int in = 0; in < 4; in++) {
            const int col = n0 + wn + in * 16 + l16;
            const float bvv = bias[col];
#pragma unroll
            for (int im = 0; im < 4; im++) {
                const int rowl = m0 + wm + im * 16 + quad * 4;
#pragma unroll
                for (int r = 0; r < 4; r++)
                    Cb[(size_t)(rowl + r) * KCAT + col] =
                        f2b(gelu_exact(acc[im][in][r] + bvv));
            }
        }
        if (m_base == 0 && blockIdx.x == 0 && blockIdx.y == 0 && tid == 0) {
            float aux = 0.0f;
            for (int e = 0; e < 8; e++) aux += accbuf[e] * accbuf[8 + e];
            outAux[0] = aux * 8.0f / ((float)NTOK * (float)NTOK);
        }
    } else {                               // feats: gelu * routing weight
        int eidx[4];
#pragma unroll
        for (int in = 0; in < 4; in++)
            eidx[in] = (n0 + wn + in * 16 - HID) / DLOW;   // uniform over l16
#pragma unroll
        for (int im = 0; im < 4; im++) {
            const int rowl = m0 + wm + im * 16 + quad * 4;
#pragma unroll
            for (int r = 0; r < 4; r++) {
                const int g = m_base + rowl + r;
                const int e0 = tokE[2 * g], e1 = tokE[2 * g + 1];
                const float w0 = tokW[2 * g], w1 = tokW[2 * g + 1];
#pragma unroll
                for (int in = 0; in < 4; in++) {
                    const int col = n0 + wn + in * 16 + l16;
                    const float m = (eidx[in] == e0) ? w0
                                  : ((eidx[in] == e1) ? w1 : 0.0f);
                    Cb[(size_t)(rowl + r) * KCAT + col] =
                        f2b(gelu_exact(acc[im][in][r]) * m);
                }
            }
        }
    }
}

// ---------------------------------------------------------------------------
// OUTPUT GEMM: acc = HU[m,:].Wcat[col,:] over a K-slice.
//   gridDim.z==1: out[b,col,nn] = acc + b2[col] + x  (full K)
//   gridDim.z==2: z=0 -> out = acc + b2 + x (K half 0)
//                 z=1 -> out2(local) = acc (K half 1)
// ---------------------------------------------------------------------------
__global__ __launch_bounds__(256)
void gemm_out(const ushort_t* __restrict__ A, const ushort_t* __restrict__ B,
              float* __restrict__ out, float* __restrict__ out2,
              const float* __restrict__ bias, const float* __restrict__ X,
              int m_base, int kslice)
{
    __shared__ __align__(16) ushort_t As[128 * 64];
    __shared__ __align__(16) ushort_t Bs[128 * 64];
    const int kb = blockIdx.z * kslice;
    GEMM_CORE(A, B, KCAT, kb, kb + kslice)

    const bool main_z = (blockIdx.z == 0);
#pragma unroll
    for (int in = 0; in < 4; in++) {
        const int col = n0 + wn + in * 16 + l16;
        const float bvv = bias[col];
#pragma unroll
        for (int im = 0; im < 4; im++) {
            const int grow = m_base + m0 + wm + im * 16 + quad * 4;
            float4 v;
            v.x = acc[im][in][0]; v.y = acc[im][in][1];
            v.z = acc[im][in][2]; v.w = acc[im][in][3];
            if (main_z) {
                const int bb = grow >> 10, nn = grow & 1023;
                const size_t base = ((size_t)bb * DIM + col) * NPB + nn;
                const float4 xv = *(const float4*)(X + base);
                v.x += bvv + xv.x; v.y += bvv + xv.y;
                v.z += bvv + xv.z; v.w += bvv + xv.w;
                *(float4*)(out + base) = v;
            } else {
                const int lt = grow - m_base;
                const int lb = lt >> 10, nn = lt & 1023;
                const size_t base = ((size_t)lb * DIM + col) * NPB + nn;
                *(float4*)(out2 + base) = v;
            }
        }
    }
}

// out[m_base*DIM + i] += out2[i]  (float4, over chunk*DIM elems)
__global__ void combine_kernel(float* __restrict__ out,
                               const float* __restrict__ out2, int m_base)
{
    const int i = blockIdx.x * 256 + threadIdx.x;
    float4 a = ((const float4*)(out + (size_t)m_base * DIM))[i];
    const float4 b = ((const float4*)out2)[i];
    a.x += b.x; a.y += b.y; a.z += b.z; a.w += b.w;
    ((float4*)(out + (size_t)m_base * DIM))[i] = a;
}

// ---------------------------------------------------------------------------
// x f32 [B,C,N] -> XTbf bf16 [T,C]
// ---------------------------------------------------------------------------
__global__ void transpose_x_cvt(const float* __restrict__ x, ushort_t* __restrict__ XT)
{
    __shared__ ushort_t tile[32][33];
    const int tx = threadIdx.x, ty = threadIdx.y;
    const int n0 = blockIdx.x * 32, c0 = blockIdx.y * 32, b = blockIdx.z;
#pragma unroll
    for (int j = 0; j < 4; j++)
        tile[ty + 8 * j][tx] = f2b(x[((size_t)b * DIM + c0 + ty + 8 * j) * NPB + n0 + tx]);
    __syncthreads();
#pragma unroll
    for (int j = 0; j < 4; j++)
        XT[((size_t)b * NPB + n0 + ty + 8 * j) * DIM + c0 + tx] = tile[tx][ty + 8 * j];
}

// w_up f32 [KD][DIM] -> Wcat[:, HID:KCAT] bf16 (row stride KCAT)
__global__ void transpose_wup_cat(const float* __restrict__ src, ushort_t* __restrict__ Wcat)
{
    __shared__ ushort_t tile[32][33];
    const int tx = threadIdx.x, ty = threadIdx.y;
    const int c0 = blockIdx.x * 32, k0 = blockIdx.y * 32;
#pragma unroll
    for (int j = 0; j < 4; j++)
        tile[ty + 8 * j][tx] = f2b(src[(size_t)(k0 + ty + 8 * j) * DIM + c0 + tx]);
    __syncthreads();
#pragma unroll
    for (int j = 0; j < 4; j++)
        Wcat[(size_t)(c0 + ty + 8 * j) * KCAT + HID + k0 + tx] = tile[tx][ty + 8 * j];
}

// w2 f32 [DIM][HID] -> Wcat[:, 0:HID] bf16 (row stride KCAT)
__global__ void cvt_w2_cat(const float* __restrict__ w2, ushort_t* __restrict__ Wcat)
{
    const int i = blockIdx.x * 256 + threadIdx.x;
    const int c = i / (HID / 4), h = (i % (HID / 4)) * 4;
    const float4 v = *(const float4*)(w2 + (size_t)c * HID + h);
    uint2 p;
    p.x = (unsigned)f2b(v.x) | ((unsigned)f2b(v.y) << 16);
    p.y = (unsigned)f2b(v.z) | ((unsigned)f2b(v.w) << 16);
    *(uint2*)(Wcat + (size_t)c * KCAT + h) = p;
}

// merged f32->bf16 of [w1 ; wdn] into Win (flat concat)
__global__ void cvt_win(const float* __restrict__ w1, const float* __restrict__ wdn,
                        ushort_t* __restrict__ Win)
{
    const int i = blockIdx.x * 256 + threadIdx.x;       // < KCAT*DIM/4
    const int n1 = HID * DIM / 4;
    const float4 v = (i < n1) ? ((const float4*)w1)[i]
                              : ((const float4*)wdn)[i - n1];
    uint2 p;
    p.x = (unsigned)f2b(v.x) | ((unsigned)f2b(v.y) << 16);
    p.y = (unsigned)f2b(v.z) | ((unsigned)f2b(v.w) << 16);
    ((uint2*)Win)[i] = p;
}

// ---------------------------------------------------------------------------
// Weff[e][c] = sum_d w_down[e*192+d][c] * rw[d]   (all f32, exact fold)
// ---------------------------------------------------------------------------
__global__ __launch_bounds__(256)
void weff_kernel(const float* __restrict__ wdn, const float* __restrict__ rw,
                 float* __restrict__ Weff)
{
    const int idx = blockIdx.x * 256 + threadIdx.x;
    const int e = idx / DIM, c = idx % DIM;
    float s = 0.0f;
    for (int d = 0; d < DLOW; d++)
        s += wdn[(size_t)(e * DLOW + d) * DIM + c] * rw[d];
    Weff[idx] = s;
}

// ---------------------------------------------------------------------------
// Router (all f32): thread t owns one token. logits -> softmax -> top2 -> aux
// ---------------------------------------------------------------------------
__global__ __launch_bounds__(256)
void router_kernel(const float* __restrict__ x, const float* __restrict__ Weff,
                   int* __restrict__ tokE, float* __restrict__ tokW,
                   float* __restrict__ accbuf)
{
    __shared__ float sW[NEXP * DIM];
    __shared__ float sAcc[16];
    const int tid = threadIdx.x;
    for (int i = tid; i < NEXP * DIM; i += 256) sW[i] = Weff[i];
    if (tid < 16) sAcc[tid] = 0.0f;
    __syncthreads();

    const int t = blockIdx.x * 256 + tid;
    const int b = t >> 10, n = t & 1023;
    const float* xb = x + (size_t)b * DIM * NPB + n;

    float lg[8];
#pragma unroll
    for (int e = 0; e < 8; e++) lg[e] = 0.0f;
    for (int c = 0; c < DIM; c++) {
        const float xv = xb[(size_t)c * NPB];
#pragma unroll
        for (int e = 0; e < 8; e++) lg[e] += xv * sW[e * DIM + c];
    }

    float mx = lg[0];
#pragma unroll
    for (int e = 1; e < 8; e++) mx = fmaxf(mx, lg[e]);
    float pr[8], s = 0.0f;
#pragma unroll
    for (int e = 0; e < 8; e++) { pr[e] = expf(lg[e] - mx); s += pr[e]; }
    const float inv = 1.0f / s;
#pragma unroll
    for (int e = 0; e < 8; e++) pr[e] *= inv;
    int e0 = 0;
#pragma unroll
    for (int e = 1; e < 8; e++) if (pr[e] > pr[e0]) e0 = e;
    int e1 = (e0 == 0) ? 1 : 0;
#pragma unroll
    for (int e = 0; e < 8; e++) if (e != e0 && pr[e] > pr[e1]) e1 = e;
    const float wsum = pr[e0] + pr[e1];
    tokE[2 * t + 0] = e0;  tokE[2 * t + 1] = e1;
    tokW[2 * t + 0] = pr[e0] / wsum;  tokW[2 * t + 1] = pr[e1] / wsum;

#pragma unroll
    for (int e = 0; e < 8; e++) atomicAdd(&sAcc[e], pr[e]);
    atomicAdd(&sAcc[8 + e0], 1.0f);
    atomicAdd(&sAcc[8 + e1], 1.0f);
    __syncthreads();
    if (tid < 16) atomicAdd(&accbuf[tid], sAcc[tid]);
}

// ---------------------------------------------------------------------------
extern "C" void kernel_launch(void* const* d_in, const int* in_sizes, int n_in,
                              void* d_out, int out_size, void* d_ws, size_t ws_size,
                              hipStream_t stream)
{
    (void)in_sizes; (void)n_in; (void)out_size;

    const float* x   = (const float*)d_in[0];
    const float* w1  = (const float*)d_in[1];
    const float* b1  = (const float*)d_in[2];
    const float* w2  = (const float*)d_in[3];
    const float* b2  = (const float*)d_in[4];
    const float* wdn = (const float*)d_in[5];
    const float* rw  = (const float*)d_in[6];
    const float* wup = (const float*)d_in[7];
    float* out = (float*)d_out;

    char* ws = (char*)d_ws;
    size_t off = 0;
    ushort_t* XTbf = (ushort_t*)(ws + off); off += (size_t)NTOK * DIM * 2;   // 12.6 MB
    ushort_t* Win  = (ushort_t*)(ws + off); off += (size_t)KCAT * DIM * 2;   //  7.1 MB
    ushort_t* Wcat = (ushort_t*)(ws + off); off += (size_t)DIM * KCAT * 2;   //  7.1 MB
    float*    Weff = (float*)  (ws + off);  off += (size_t)NEXP * DIM * 4;
    int*      tokE = (int*)    (ws + off);  off += (size_t)NTOK * 2 * 4;
    float*    tokW = (float*)  (ws + off);  off += (size_t)NTOK * 2 * 4;
    float*    accb = (float*)  (ws + off);  off += 256;

    // tier: largest chunk + optional K-split scratch (pure fn of ws_size)
    auto need = [&](int ch, bool sp) {
        return off + (size_t)ch * KCAT * 2 + (sp ? (size_t)ch * DIM * 4 : 0);
    };
    int chunk; bool split;
    if      (ws_size >= need(NTOK, true))      { chunk = NTOK;     split = true;  }
    else if (ws_size >= need(NTOK, false))     { chunk = NTOK;     split = false; }
    else if (ws_size >= need(NTOK / 2, true))  { chunk = NTOK / 2; split = true;  }
    else if (ws_size >= need(NTOK / 2, false)) { chunk = NTOK / 2; split = false; }
    else                                       { chunk = NTOK / 4; split = false; }

    ushort_t* HU   = (ushort_t*)(ws + off);                       // chunk*KCAT bf16
    float*    out2 = (float*)(ws + off + (size_t)chunk * KCAT * 2); // chunk*DIM f32

    const dim3 tb(32, 8);
    transpose_x_cvt  <<<dim3(32, 24, 8), tb, 0, stream>>>(x, XTbf);
    transpose_wup_cat<<<dim3(24, 48),    tb, 0, stream>>>(wup, Wcat);
    cvt_w2_cat<<<DIM * HID / 4 / 256, 256, 0, stream>>>(w2, Wcat);
    cvt_win   <<<KCAT * DIM / 4 / 256, 256, 0, stream>>>(w1, wdn, Win);
    weff_kernel<<<NEXP * DIM / 256, 256, 0, stream>>>(wdn, rw, Weff);

    hipMemsetAsync(accb, 0, 64, stream);
    router_kernel<<<NTOK / 256, 256, 0, stream>>>(x, Weff, tokE, tokW, accb);

    for (int c = 0; c < NTOK / chunk; c++) {
        const ushort_t* Ax = XTbf + (size_t)c * chunk * DIM;
        const int m_base = c * chunk;
        // HU = [gelu(XT@w1^T + b1) | gelu(XT@wdn^T) * routing weight]
        gemm_in<<<dim3(KCAT / 128, chunk / 128), 256, 0, stream>>>(
            Ax, Win, HU, b1, tokE, tokW, accb, out + (size_t)NTOK * DIM, m_base);
        // out = HU @ Wcat^T + b2 + x   (optionally split K across z)
        if (split) {
            gemm_out<<<dim3(DIM / 128, chunk / 128, 2), 256, 0, stream>>>(
                HU, Wcat, out, out2, b2, x, m_base, KCAT / 2);
            combine_kernel<<<chunk * DIM / 4 / 256, 256, 0, stream>>>(out, out2, m_base);
        } else {
            gemm_out<<<dim3(DIM / 128, chunk / 128, 1), 256, 0, stream>>>(
                HU, Wcat, out, nullptr, b2, x, m_base, KCAT);
        }
    }
}

// Round 8
// 354.929 us; speedup vs baseline: 1.1540x; 1.1540x over previous
//
#include <hip/hip_runtime.h>
#include <cstdint>
#include <cmath>

#define DIM   768
#define HID   3072
#define NEXP  8
#define DLOW  192
#define NPB   1024            // tokens per image (32*32)
#define NTOK  8192
#define KD    1536            // NEXP*DLOW
#define KCAT  4608            // HID + KD

typedef unsigned short ushort_t;
typedef short   short8  __attribute__((ext_vector_type(8)));
typedef float   float4v __attribute__((ext_vector_type(4)));

__device__ inline ushort_t f2b(float f) {
    union { float f; unsigned int i; } v; v.f = f;
    unsigned int x = v.i;
    return (ushort_t)((x + 0x7fffu + ((x >> 16) & 1u)) >> 16);   // RNE
}
__device__ inline float b2f(ushort_t u) {
    union { unsigned int i; float f; } v; v.i = ((unsigned int)u) << 16; return v.f;
}
// tanh-form GELU (max |err| vs erf-GELU ~3e-4, below bf16 rounding of HU):
// gelu(x) = x * sigmoid(1.5957691 * x * (1 + 0.044715 x^2))
__device__ inline float gelu_fast(float x) {
    const float z = 1.5957691216057308f * x * __builtin_fmaf(0.044715f * x, x, 1.0f);
    return x * __builtin_amdgcn_rcpf(1.0f + __expf(-z));
}

// async global->LDS, 16 B per lane (global_load_lds_dwordx4)
__device__ __forceinline__ void async_ld16(const ushort_t* g, ushort_t* l) {
    __builtin_amdgcn_global_load_lds(
        (const __attribute__((address_space(1))) void*)g,
        (__attribute__((address_space(3))) void*)l,
        16, 0, 0);
}

// ===========================================================================
// Shared BK=64 XOR-swizzled MFMA core (0 LDS bank conflicts, r5-r7 proven).
// ===========================================================================
#define GEMM_CORE(A, B, K, kb, ke)                                            \
    const int tid  = threadIdx.x;                                             \
    const int lane = tid & 63;                                                \
    const int wave = tid >> 6;                                                \
    const int quad = lane >> 4;                                               \
    const int l16  = lane & 15;                                               \
    const int wm   = (wave >> 1) * 64;                                        \
    const int wn   = (wave & 1) * 64;                                         \
    const int m0   = blockIdx.y * 128;                                        \
    const int n0   = blockIdx.x * 128;                                        \
    float4v acc[4][4];                                                        \
    _Pragma("unroll")                                                         \
    for (int i = 0; i < 4; i++)                                               \
        _Pragma("unroll")                                                     \
        for (int j = 0; j < 4; j++) acc[i][j] = (float4v)0.0f;                \
    const ushort_t* ga[4]; const ushort_t* gb[4];                             \
    ushort_t* la[4]; ushort_t* lb[4];                                         \
    _Pragma("unroll")                                                         \
    for (int j = 0; j < 4; j++) {                                             \
        const int f = j * 256 + tid;                                          \
        const int mm = f >> 3;                                                \
        const int gs = ((f & 7) ^ (mm & 7)) * 8;                              \
        ga[j] = A + (size_t)(m0 + mm) * K + gs;                               \
        gb[j] = B + (size_t)(n0 + mm) * K + gs;                               \
        la[j] = &As[f * 8];                                                   \
        lb[j] = &Bs[f * 8];                                                   \
    }                                                                         \
    const ushort_t* pa[2][4]; const ushort_t* pb[2][4];                       \
    _Pragma("unroll")                                                         \
    for (int kh = 0; kh < 2; kh++)                                            \
        _Pragma("unroll")                                                     \
        for (int i = 0; i < 4; i++) {                                         \
            const int ra = wm + i * 16 + l16;                                 \
            pa[kh][i] = &As[ra * 64 + (((quad + 4 * kh) ^ (ra & 7)) * 8)];    \
            const int rb = wn + i * 16 + l16;                                 \
            pb[kh][i] = &Bs[rb * 64 + (((quad + 4 * kh) ^ (rb & 7)) * 8)];    \
        }                                                                     \
    for (int k0 = (kb); k0 < (ke); k0 += 64) {                                \
        __syncthreads();                                                      \
        _Pragma("unroll")                                                     \
        for (int j = 0; j < 4; j++) async_ld16(ga[j] + k0, la[j]);            \
        _Pragma("unroll")                                                     \
        for (int j = 0; j < 4; j++) async_ld16(gb[j] + k0, lb[j]);            \
        __syncthreads();                                                      \
        _Pragma("unroll")                                                     \
        for (int kh = 0; kh < 2; kh++) {                                      \
            short8 af[4], bv[4];                                              \
            _Pragma("unroll")                                                 \
            for (int i = 0; i < 4; i++) af[i] = *(const short8*)pa[kh][i];    \
            _Pragma("unroll")                                                 \
            for (int i = 0; i < 4; i++) bv[i] = *(const short8*)pb[kh][i];    \
            _Pragma("unroll")                                                 \
            for (int im = 0; im < 4; im++)                                    \
                _Pragma("unroll")                                             \
                for (int in = 0; in < 4; in++)                                \
                    acc[im][in] = __builtin_amdgcn_mfma_f32_16x16x32_bf16(    \
                        af[im], bv[in], acc[im][in], 0, 0, 0);                \
        }                                                                     \
    }

// ---------------------------------------------------------------------------
// INPUT GEMM: HU[m, col] = XT[m,:].Win[col,:]  (K=768), fused epilogue:
//   col <  HID : bf16(gelu(acc + b1[col]))
//   col >= HID : bf16(gelu(acc) * routing_weight(token, expert(col)))
// Block (0,0) of chunk 0 also writes the aux-loss scalar.
// ---------------------------------------------------------------------------
__global__ __launch_bounds__(256)
void gemm_in(const ushort_t* __restrict__ A, const ushort_t* __restrict__ B,
             ushort_t* __restrict__ Cb, const float* __restrict__ bias,
             const int* __restrict__ tokE, const float* __restrict__ tokW,
             const float* __restrict__ accbuf, float* __restrict__ outAux,
             int m_base)
{
    __shared__ __align__(16) ushort_t As[128 * 64];
    __shared__ __align__(16) ushort_t Bs[128 * 64];
    GEMM_CORE(A, B, DIM, 0, DIM)

    if (n0 < HID) {                        // shared-expert hidden: gelu + b1
#pragma unroll
        for (int in = 0; in < 4; in++) {
            const int col = n0 + wn + in * 16 + l16;
            const float bvv = bias[col];
#pragma unroll
            for (int im = 0; im < 4; im++) {
                const int rowl = m0 + wm + im * 16 + quad * 4;
#pragma unroll
                for (int r = 0; r < 4; r++)
                    Cb[(size_t)(rowl + r) * KCAT + col] =
                        f2b(gelu_fast(acc[im][in][r] + bvv));
            }
        }
        if (m_base == 0 && blockIdx.x == 0 && blockIdx.y == 0 && tid == 0) {
            float aux = 0.0f;
            for (int e = 0; e < 8; e++) aux += accbuf[e] * accbuf[8 + e];
            outAux[0] = aux * 8.0f / ((float)NTOK * (float)NTOK);
        }
    } else {                               // feats: gelu * routing weight
        int eidx[4];
#pragma unroll
        for (int in = 0; in < 4; in++)
            eidx[in] = (n0 + wn + in * 16 - HID) / DLOW;   // uniform over l16
#pragma unroll
        for (int im = 0; im < 4; im++) {
            const int rowl = m0 + wm + im * 16 + quad * 4;
#pragma unroll
            for (int r = 0; r < 4; r++) {
                const int g = m_base + rowl + r;
                const int e0 = tokE[2 * g], e1 = tokE[2 * g + 1];
                const float w0 = tokW[2 * g], w1 = tokW[2 * g + 1];
#pragma unroll
                for (int in = 0; in < 4; in++) {
                    const int col = n0 + wn + in * 16 + l16;
                    const float m = (eidx[in] == e0) ? w0
                                  : ((eidx[in] == e1) ? w1 : 0.0f);
                    Cb[(size_t)(rowl + r) * KCAT + col] =
                        f2b(gelu_fast(acc[im][in][r]) * m);
                }
            }
        }
    }
}

// ---------------------------------------------------------------------------
// OUTPUT GEMM (r6-proven, unsplit): acc = HU[m,:].Wcat[col,:] (K=4608)
//   out[b, col, nn] = acc + b2[col] + x[b, col, nn],  token m_base+m
// ---------------------------------------------------------------------------
__global__ __launch_bounds__(256)
void gemm_out(const ushort_t* __restrict__ A, const ushort_t* __restrict__ B,
              float* __restrict__ out, const float* __restrict__ bias,
              const float* __restrict__ X, int m_base)
{
    __shared__ __align__(16) ushort_t As[128 * 64];
    __shared__ __align__(16) ushort_t Bs[128 * 64];
    GEMM_CORE(A, B, KCAT, 0, KCAT)

#pragma unroll
    for (int in = 0; in < 4; in++) {
        const int col = n0 + wn + in * 16 + l16;
        const float bvv = bias[col];
#pragma unroll
        for (int im = 0; im < 4; im++) {
            const int grow = m_base + m0 + wm + im * 16 + quad * 4;
            const int bb = grow >> 10, nn = grow & 1023;
            const size_t base = ((size_t)bb * DIM + col) * NPB + nn;
            const float4 xv = *(const float4*)(X + base);
            float4 v;
            v.x = acc[im][in][0] + bvv + xv.x;
            v.y = acc[im][in][1] + bvv + xv.y;
            v.z = acc[im][in][2] + bvv + xv.z;
            v.w = acc[im][in][3] + bvv + xv.w;
            *(float4*)(out + base) = v;
        }
    }
}

// ---------------------------------------------------------------------------
// x f32 [B,C,N] -> XTbf bf16 [T,C]
// ---------------------------------------------------------------------------
__global__ void transpose_x_cvt(const float* __restrict__ x, ushort_t* __restrict__ XT)
{
    __shared__ ushort_t tile[32][33];
    const int tx = threadIdx.x, ty = threadIdx.y;
    const int n0 = blockIdx.x * 32, c0 = blockIdx.y * 32, b = blockIdx.z;
#pragma unroll
    for (int j = 0; j < 4; j++)
        tile[ty + 8 * j][tx] = f2b(x[((size_t)b * DIM + c0 + ty + 8 * j) * NPB + n0 + tx]);
    __syncthreads();
#pragma unroll
    for (int j = 0; j < 4; j++)
        XT[((size_t)b * NPB + n0 + ty + 8 * j) * DIM + c0 + tx] = tile[tx][ty + 8 * j];
}

// w_up f32 [KD][DIM] -> Wcat[:, HID:KCAT] bf16 (row stride KCAT)
__global__ void transpose_wup_cat(const float* __restrict__ src, ushort_t* __restrict__ Wcat)
{
    __shared__ ushort_t tile[32][33];
    const int tx = threadIdx.x, ty = threadIdx.y;
    const int c0 = blockIdx.x * 32, k0 = blockIdx.y * 32;
#pragma unroll
    for (int j = 0; j < 4; j++)
        tile[ty + 8 * j][tx] = f2b(src[(size_t)(k0 + ty + 8 * j) * DIM + c0 + tx]);
    __syncthreads();
#pragma unroll
    for (int j = 0; j < 4; j++)
        Wcat[(size_t)(c0 + ty + 8 * j) * KCAT + HID + k0 + tx] = tile[tx][ty + 8 * j];
}

// merged weight prep:
//   blocks [0, NB_W2): w2 f32 [DIM][HID] -> Wcat[:, 0:HID] (row stride KCAT)
//   blocks [NB_W2, ..): [w1 ; wdn] f32 -> Win flat bf16
#define NB_W2  (DIM * HID / 4 / 256)
#define NB_WIN (KCAT * DIM / 4 / 256)
__global__ void cvt_weights(const float* __restrict__ w2, const float* __restrict__ w1,
                            const float* __restrict__ wdn,
                            ushort_t* __restrict__ Wcat, ushort_t* __restrict__ Win)
{
    const int blk = blockIdx.x;
    if (blk < NB_W2) {
        const int i = blk * 256 + threadIdx.x;
        const int c = i / (HID / 4), h = (i % (HID / 4)) * 4;
        const float4 v = *(const float4*)(w2 + (size_t)c * HID + h);
        uint2 p;
        p.x = (unsigned)f2b(v.x) | ((unsigned)f2b(v.y) << 16);
        p.y = (unsigned)f2b(v.z) | ((unsigned)f2b(v.w) << 16);
        *(uint2*)(Wcat + (size_t)c * KCAT + h) = p;
    } else {
        const int i = (blk - NB_W2) * 256 + threadIdx.x;
        const int n1 = HID * DIM / 4;
        const float4 v = (i < n1) ? ((const float4*)w1)[i]
                                  : ((const float4*)wdn)[i - n1];
        uint2 p;
        p.x = (unsigned)f2b(v.x) | ((unsigned)f2b(v.y) << 16);
        p.y = (unsigned)f2b(v.z) | ((unsigned)f2b(v.w) << 16);
        ((uint2*)Win)[i] = p;
    }
}

// ---------------------------------------------------------------------------
// Weff[e][c] = sum_d w_down[e*192+d][c] * rw[d]   (all f32, exact fold)
// ---------------------------------------------------------------------------
__global__ __launch_bounds__(256)
void weff_kernel(const float* __restrict__ wdn, const float* __restrict__ rw,
                 float* __restrict__ Weff)
{
    const int idx = blockIdx.x * 256 + threadIdx.x;
    const int e = idx / DIM, c = idx % DIM;
    float s = 0.0f;
    for (int d = 0; d < DLOW; d++)
        s += wdn[(size_t)(e * DLOW + d) * DIM + c] * rw[d];
    Weff[idx] = s;
}

// ---------------------------------------------------------------------------
// Router (all f32): thread t owns one token. logits -> softmax -> top2 -> aux
// ---------------------------------------------------------------------------
__global__ __launch_bounds__(256)
void router_kernel(const float* __restrict__ x, const float* __restrict__ Weff,
                   int* __restrict__ tokE, float* __restrict__ tokW,
                   float* __restrict__ accbuf)
{
    __shared__ float sW[NEXP * DIM];
    __shared__ float sAcc[16];
    const int tid = threadIdx.x;
    for (int i = tid; i < NEXP * DIM; i += 256) sW[i] = Weff[i];
    if (tid < 16) sAcc[tid] = 0.0f;
    __syncthreads();

    const int t = blockIdx.x * 256 + tid;
    const int b = t >> 10, n = t & 1023;
    const float* xb = x + (size_t)b * DIM * NPB + n;

    float lg[8];
#pragma unroll
    for (int e = 0; e < 8; e++) lg[e] = 0.0f;
    for (int c = 0; c < DIM; c++) {
        const float xv = xb[(size_t)c * NPB];
#pragma unroll
        for (int e = 0; e < 8; e++) lg[e] += xv * sW[e * DIM + c];
    }

    float mx = lg[0];
#pragma unroll
    for (int e = 1; e < 8; e++) mx = fmaxf(mx, lg[e]);
    float pr[8], s = 0.0f;
#pragma unroll
    for (int e = 0; e < 8; e++) { pr[e] = expf(lg[e] - mx); s += pr[e]; }
    const float inv = 1.0f / s;
#pragma unroll
    for (int e = 0; e < 8; e++) pr[e] *= inv;
    int e0 = 0;
#pragma unroll
    for (int e = 1; e < 8; e++) if (pr[e] > pr[e0]) e0 = e;
    int e1 = (e0 == 0) ? 1 : 0;
#pragma unroll
    for (int e = 0; e < 8; e++) if (e != e0 && pr[e] > pr[e1]) e1 = e;
    const float wsum = pr[e0] + pr[e1];
    tokE[2 * t + 0] = e0;  tokE[2 * t + 1] = e1;
    tokW[2 * t + 0] = pr[e0] / wsum;  tokW[2 * t + 1] = pr[e1] / wsum;

#pragma unroll
    for (int e = 0; e < 8; e++) atomicAdd(&sAcc[e], pr[e]);
    atomicAdd(&sAcc[8 + e0], 1.0f);
    atomicAdd(&sAcc[8 + e1], 1.0f);
    __syncthreads();
    if (tid < 16) atomicAdd(&accbuf[tid], sAcc[tid]);
}

// ---------------------------------------------------------------------------
extern "C" void kernel_launch(void* const* d_in, const int* in_sizes, int n_in,
                              void* d_out, int out_size, void* d_ws, size_t ws_size,
                              hipStream_t stream)
{
    (void)in_sizes; (void)n_in; (void)out_size;

    const float* x   = (const float*)d_in[0];
    const float* w1  = (const float*)d_in[1];
    const float* b1  = (const float*)d_in[2];
    const float* w2  = (const float*)d_in[3];
    const float* b2  = (const float*)d_in[4];
    const float* wdn = (const float*)d_in[5];
    const float* rw  = (const float*)d_in[6];
    const float* wup = (const float*)d_in[7];
    float* out = (float*)d_out;

    char* ws = (char*)d_ws;
    size_t off = 0;
    ushort_t* XTbf = (ushort_t*)(ws + off); off += (size_t)NTOK * DIM * 2;   // 12.6 MB
    ushort_t* Win  = (ushort_t*)(ws + off); off += (size_t)KCAT * DIM * 2;   //  7.1 MB
    ushort_t* Wcat = (ushort_t*)(ws + off); off += (size_t)DIM * KCAT * 2;   //  7.1 MB
    float*    Weff = (float*)  (ws + off);  off += (size_t)NEXP * DIM * 4;
    int*      tokE = (int*)    (ws + off);  off += (size_t)NTOK * 2 * 4;
    float*    tokW = (float*)  (ws + off);  off += (size_t)NTOK * 2 * 4;
    float*    accb = (float*)  (ws + off);  off += 256;

    // largest token-chunk that fits (graph-safe: pure function of ws_size)
    int chunk = NTOK / 4;
    if      (ws_size >= off + (size_t)NTOK * KCAT * 2)       chunk = NTOK;
    else if (ws_size >= off + (size_t)(NTOK / 2) * KCAT * 2) chunk = NTOK / 2;
    ushort_t* HU = (ushort_t*)(ws + off);                    // chunk*KCAT bf16

    const dim3 tb(32, 8);
    transpose_x_cvt  <<<dim3(32, 24, 8), tb, 0, stream>>>(x, XTbf);
    transpose_wup_cat<<<dim3(24, 48),    tb, 0, stream>>>(wup, Wcat);
    cvt_weights<<<NB_W2 + NB_WIN, 256, 0, stream>>>(w2, w1, wdn, Wcat, Win);
    weff_kernel<<<NEXP * DIM / 256, 256, 0, stream>>>(wdn, rw, Weff);

    hipMemsetAsync(accb, 0, 64, stream);
    router_kernel<<<NTOK / 256, 256, 0, stream>>>(x, Weff, tokE, tokW, accb);

    for (int c = 0; c < NTOK / chunk; c++) {
        const ushort_t* Ax = XTbf + (size_t)c * chunk * DIM;
        const int m_base = c * chunk;
        // HU = [gelu(XT@w1^T + b1) | gelu(XT@wdn^T) * routing weight]
        gemm_in<<<dim3(KCAT / 128, chunk / 128), 256, 0, stream>>>(
            Ax, Win, HU, b1, tokE, tokW, accb, out + (size_t)NTOK * DIM, m_base);
        // out = HU @ Wcat^T + b2 + x
        gemm_out<<<dim3(DIM / 128, chunk / 128), 256, 0, stream>>>(
            HU, Wcat, out, b2, x, m_base);
    }
}

// Round 9
// 341.949 us; speedup vs baseline: 1.1978x; 1.0380x over previous
//
#include <hip/hip_runtime.h>
#include <cstdint>
#include <cmath>

#define DIM   768
#define HID   3072
#define NEXP  8
#define DLOW  192
#define NPB   1024            // tokens per image (32*32)
#define NTOK  8192
#define KD    1536            // NEXP*DLOW
#define KCAT  4608            // HID + KD

typedef unsigned short ushort_t;
typedef short   short8  __attribute__((ext_vector_type(8)));
typedef float   float4v __attribute__((ext_vector_type(4)));

__device__ inline ushort_t f2b(float f) {
    union { float f; unsigned int i; } v; v.f = f;
    unsigned int x = v.i;
    return (ushort_t)((x + 0x7fffu + ((x >> 16) & 1u)) >> 16);   // RNE
}
__device__ inline float b2f(ushort_t u) {
    union { unsigned int i; float f; } v; v.i = ((unsigned int)u) << 16; return v.f;
}
// tanh-form GELU (max |err| vs erf-GELU ~3e-4, below bf16 rounding of HU)
__device__ inline float gelu_fast(float x) {
    const float z = 1.5957691216057308f * x * __builtin_fmaf(0.044715f * x, x, 1.0f);
    return x * __builtin_amdgcn_rcpf(1.0f + __expf(-z));
}

// async global->LDS, 16 B per lane (global_load_lds_dwordx4)
__device__ __forceinline__ void async_ld16(const ushort_t* g, ushort_t* l) {
    __builtin_amdgcn_global_load_lds(
        (const __attribute__((address_space(1))) void*)g,
        (__attribute__((address_space(3))) void*)l,
        16, 0, 0);
}

// ---------------------------------------------------------------------------
// INPUT GEMM: 256x128 tile, 512 threads (8 waves, 4x2), BK=64, XOR swizzle.
// HU[m, col] = XT[m,:].Win[col,:]  (K=768), fused epilogue:
//   col <  HID : bf16(gelu(acc + b1[col]))
//   col >= HID : bf16(gelu(acc) * routing_weight(token, expert(col)))
// Block (0,0) of chunk 0 also writes the aux-loss scalar.
// ---------------------------------------------------------------------------
__global__ __launch_bounds__(512)
void gemm_in(const ushort_t* __restrict__ A, const ushort_t* __restrict__ B,
             ushort_t* __restrict__ Cb, const float* __restrict__ bias,
             const int* __restrict__ tokE, const float* __restrict__ tokW,
             const float* __restrict__ accbuf, float* __restrict__ outAux,
             int m_base)
{
    __shared__ __align__(16) ushort_t As[256 * 64];   // 32 KB
    __shared__ __align__(16) ushort_t Bs[128 * 64];   // 16 KB

    const int tid  = threadIdx.x;
    const int lane = tid & 63;
    const int wave = tid >> 6;           // 0..7
    const int quad = lane >> 4;
    const int l16  = lane & 15;
    const int wm   = (wave >> 1) * 64;   // 0,64,128,192
    const int wn   = (wave & 1) * 64;    // 0,64
    const int m0   = blockIdx.y * 256;
    const int n0   = blockIdx.x * 128;

    float4v acc[4][4];
#pragma unroll
    for (int i = 0; i < 4; i++)
#pragma unroll
        for (int j = 0; j < 4; j++) acc[i][j] = (float4v)0.0f;

    // staging: LDS slot f holds k-group (f&7)^(row&7) of row f>>3
    const ushort_t* ga[4]; ushort_t* la[4];
#pragma unroll
    for (int j = 0; j < 4; j++) {
        const int f = j * 512 + tid;               // [0, 2048)
        const int mm = f >> 3;                     // [0, 256)
        const int gs = ((f & 7) ^ (mm & 7)) * 8;
        ga[j] = A + (size_t)(m0 + mm) * DIM + gs;
        la[j] = &As[f * 8];
    }
    const ushort_t* gb[2]; ushort_t* lb[2];
#pragma unroll
    for (int j = 0; j < 2; j++) {
        const int f = j * 512 + tid;               // [0, 1024)
        const int mm = f >> 3;                     // [0, 128)
        const int gs = ((f & 7) ^ (mm & 7)) * 8;
        gb[j] = B + (size_t)(n0 + mm) * DIM + gs;
        lb[j] = &Bs[f * 8];
    }

    // fragment LDS pointers (loop-invariant, swizzle-resolved)
    const ushort_t* pa[2][4]; const ushort_t* pb[2][4];
#pragma unroll
    for (int kh = 0; kh < 2; kh++)
#pragma unroll
        for (int i = 0; i < 4; i++) {
            const int ra = wm + i * 16 + l16;
            pa[kh][i] = &As[ra * 64 + (((quad + 4 * kh) ^ (ra & 7)) * 8)];
            const int rb = wn + i * 16 + l16;
            pb[kh][i] = &Bs[rb * 64 + (((quad + 4 * kh) ^ (rb & 7)) * 8)];
        }

    for (int k0 = 0; k0 < DIM; k0 += 64) {
        __syncthreads();
#pragma unroll
        for (int j = 0; j < 4; j++) async_ld16(ga[j] + k0, la[j]);
#pragma unroll
        for (int j = 0; j < 2; j++) async_ld16(gb[j] + k0, lb[j]);
        __syncthreads();
#pragma unroll
        for (int kh = 0; kh < 2; kh++) {
            short8 af[4], bv[4];
#pragma unroll
            for (int i = 0; i < 4; i++) af[i] = *(const short8*)pa[kh][i];
#pragma unroll
            for (int i = 0; i < 4; i++) bv[i] = *(const short8*)pb[kh][i];
#pragma unroll
            for (int im = 0; im < 4; im++)
#pragma unroll
                for (int in = 0; in < 4; in++)
                    acc[im][in] = __builtin_amdgcn_mfma_f32_16x16x32_bf16(
                        af[im], bv[in], acc[im][in], 0, 0, 0);
        }
    }

    if (n0 < HID) {                        // shared-expert hidden: gelu + b1
#pragma unroll
        for (int in = 0; in < 4; in++) {
            const int col = n0 + wn + in * 16 + l16;
            const float bvv = bias[col];
#pragma unroll
            for (int im = 0; im < 4; im++) {
                const int rowl = m0 + wm + im * 16 + quad * 4;
#pragma unroll
                for (int r = 0; r < 4; r++)
                    Cb[(size_t)(rowl + r) * KCAT + col] =
                        f2b(gelu_fast(acc[im][in][r] + bvv));
            }
        }
        if (m_base == 0 && blockIdx.x == 0 && blockIdx.y == 0 && tid == 0) {
            float aux = 0.0f;
            for (int e = 0; e < 8; e++) aux += accbuf[e] * accbuf[8 + e];
            outAux[0] = aux * 8.0f / ((float)NTOK * (float)NTOK);
        }
    } else {                               // feats: gelu * routing weight
        int eidx[4];
#pragma unroll
        for (int in = 0; in < 4; in++)
            eidx[in] = (n0 + wn + in * 16 - HID) / DLOW;   // uniform over l16
#pragma unroll
        for (int im = 0; im < 4; im++) {
            const int rowl = m0 + wm + im * 16 + quad * 4;
#pragma unroll
            for (int r = 0; r < 4; r++) {
                const int g = m_base + rowl + r;
                const int e0 = tokE[2 * g], e1 = tokE[2 * g + 1];
                const float w0 = tokW[2 * g], w1 = tokW[2 * g + 1];
#pragma unroll
                for (int in = 0; in < 4; in++) {
                    const int col = n0 + wn + in * 16 + l16;
                    const float m = (eidx[in] == e0) ? w0
                                  : ((eidx[in] == e1) ? w1 : 0.0f);
                    Cb[(size_t)(rowl + r) * KCAT + col] =
                        f2b(gelu_fast(acc[im][in][r]) * m);
                }
            }
        }
    }
}

// ---------------------------------------------------------------------------
// OUTPUT GEMM: 64x128 tile, 256 threads (4 waves over N), BK=64, K=4608.
//   out[b, col, nn] = HU[m,:].Wcat[col,:] + b2[col] + x[b, col, nn]
// ---------------------------------------------------------------------------
__global__ __launch_bounds__(256)
void gemm_out(const ushort_t* __restrict__ A, const ushort_t* __restrict__ B,
              float* __restrict__ out, const float* __restrict__ bias,
              const float* __restrict__ X, int m_base)
{
    __shared__ __align__(16) ushort_t As[64 * 64];    //  8 KB
    __shared__ __align__(16) ushort_t Bs[128 * 64];   // 16 KB

    const int tid  = threadIdx.x;
    const int lane = tid & 63;
    const int wave = tid >> 6;           // 0..3
    const int quad = lane >> 4;
    const int l16  = lane & 15;
    const int wn   = wave * 32;
    const int m0   = blockIdx.y * 64;
    const int n0   = blockIdx.x * 128;

    float4v acc[4][2];
#pragma unroll
    for (int i = 0; i < 4; i++)
#pragma unroll
        for (int j = 0; j < 2; j++) acc[i][j] = (float4v)0.0f;

    const ushort_t* ga[2]; ushort_t* la[2];
#pragma unroll
    for (int j = 0; j < 2; j++) {
        const int f = j * 256 + tid;               // [0, 512)
        const int mm = f >> 3;                     // [0, 64)
        const int gs = ((f & 7) ^ (mm & 7)) * 8;
        ga[j] = A + (size_t)(m0 + mm) * KCAT + gs;
        la[j] = &As[f * 8];
    }
    const ushort_t* gb[4]; ushort_t* lb[4];
#pragma unroll
    for (int j = 0; j < 4; j++) {
        const int f = j * 256 + tid;               // [0, 1024)
        const int mm = f >> 3;                     // [0, 128)
        const int gs = ((f & 7) ^ (mm & 7)) * 8;
        gb[j] = B + (size_t)(n0 + mm) * KCAT + gs;
        lb[j] = &Bs[f * 8];
    }

    const ushort_t* pa[2][4]; const ushort_t* pb[2][2];
#pragma unroll
    for (int kh = 0; kh < 2; kh++) {
#pragma unroll
        for (int i = 0; i < 4; i++) {
            const int ra = i * 16 + l16;
            pa[kh][i] = &As[ra * 64 + (((quad + 4 * kh) ^ (ra & 7)) * 8)];
        }
#pragma unroll
        for (int i = 0; i < 2; i++) {
            const int rb = wn + i * 16 + l16;
            pb[kh][i] = &Bs[rb * 64 + (((quad + 4 * kh) ^ (rb & 7)) * 8)];
        }
    }

    for (int k0 = 0; k0 < KCAT; k0 += 64) {
        __syncthreads();
#pragma unroll
        for (int j = 0; j < 2; j++) async_ld16(ga[j] + k0, la[j]);
#pragma unroll
        for (int j = 0; j < 4; j++) async_ld16(gb[j] + k0, lb[j]);
        __syncthreads();
#pragma unroll
        for (int kh = 0; kh < 2; kh++) {
            short8 af[4], bv[2];
#pragma unroll
            for (int i = 0; i < 4; i++) af[i] = *(const short8*)pa[kh][i];
#pragma unroll
            for (int i = 0; i < 2; i++) bv[i] = *(const short8*)pb[kh][i];
#pragma unroll
            for (int im = 0; im < 4; im++)
#pragma unroll
                for (int in = 0; in < 2; in++)
                    acc[im][in] = __builtin_amdgcn_mfma_f32_16x16x32_bf16(
                        af[im], bv[in], acc[im][in], 0, 0, 0);
        }
    }

#pragma unroll
    for (int in = 0; in < 2; in++) {
        const int col = n0 + wn + in * 16 + l16;
        const float bvv = bias[col];
#pragma unroll
        for (int im = 0; im < 4; im++) {
            const int grow = m_base + m0 + im * 16 + quad * 4;
            const int bb = grow >> 10, nn = grow & 1023;
            const size_t base = ((size_t)bb * DIM + col) * NPB + nn;
            const float4 xv = *(const float4*)(X + base);
            float4 v;
            v.x = acc[im][in][0] + bvv + xv.x;
            v.y = acc[im][in][1] + bvv + xv.y;
            v.z = acc[im][in][2] + bvv + xv.z;
            v.w = acc[im][in][3] + bvv + xv.w;
            *(float4*)(out + base) = v;
        }
    }
}

// ---------------------------------------------------------------------------
// x f32 [B,C,N] -> XTbf bf16 [T,C]
// ---------------------------------------------------------------------------
__global__ void transpose_x_cvt(const float* __restrict__ x, ushort_t* __restrict__ XT)
{
    __shared__ ushort_t tile[32][33];
    const int tx = threadIdx.x, ty = threadIdx.y;
    const int n0 = blockIdx.x * 32, c0 = blockIdx.y * 32, b = blockIdx.z;
#pragma unroll
    for (int j = 0; j < 4; j++)
        tile[ty + 8 * j][tx] = f2b(x[((size_t)b * DIM + c0 + ty + 8 * j) * NPB + n0 + tx]);
    __syncthreads();
#pragma unroll
    for (int j = 0; j < 4; j++)
        XT[((size_t)b * NPB + n0 + ty + 8 * j) * DIM + c0 + tx] = tile[tx][ty + 8 * j];
}

// w_up f32 [KD][DIM] -> Wcat[:, HID:KCAT] bf16 (row stride KCAT)
__global__ void transpose_wup_cat(const float* __restrict__ src, ushort_t* __restrict__ Wcat)
{
    __shared__ ushort_t tile[32][33];
    const int tx = threadIdx.x, ty = threadIdx.y;
    const int c0 = blockIdx.x * 32, k0 = blockIdx.y * 32;
#pragma unroll
    for (int j = 0; j < 4; j++)
        tile[ty + 8 * j][tx] = f2b(src[(size_t)(k0 + ty + 8 * j) * DIM + c0 + tx]);
    __syncthreads();
#pragma unroll
    for (int j = 0; j < 4; j++)
        Wcat[(size_t)(c0 + ty + 8 * j) * KCAT + HID + k0 + tx] = tile[tx][ty + 8 * j];
}

// merged weight prep:
//   blocks [0, NB_W2): w2 f32 [DIM][HID] -> Wcat[:, 0:HID] (row stride KCAT)
//   blocks [NB_W2, ..): [w1 ; wdn] f32 -> Win flat bf16
#define NB_W2  (DIM * HID / 4 / 256)
#define NB_WIN (KCAT * DIM / 4 / 256)
__global__ void cvt_weights(const float* __restrict__ w2, const float* __restrict__ w1,
                            const float* __restrict__ wdn,
                            ushort_t* __restrict__ Wcat, ushort_t* __restrict__ Win)
{
    const int blk = blockIdx.x;
    if (blk < NB_W2) {
        const int i = blk * 256 + threadIdx.x;
        const int c = i / (HID / 4), h = (i % (HID / 4)) * 4;
        const float4 v = *(const float4*)(w2 + (size_t)c * HID + h);
        uint2 p;
        p.x = (unsigned)f2b(v.x) | ((unsigned)f2b(v.y) << 16);
        p.y = (unsigned)f2b(v.z) | ((unsigned)f2b(v.w) << 16);
        *(uint2*)(Wcat + (size_t)c * KCAT + h) = p;
    } else {
        const int i = (blk - NB_W2) * 256 + threadIdx.x;
        const int n1 = HID * DIM / 4;
        const float4 v = (i < n1) ? ((const float4*)w1)[i]
                                  : ((const float4*)wdn)[i - n1];
        uint2 p;
        p.x = (unsigned)f2b(v.x) | ((unsigned)f2b(v.y) << 16);
        p.y = (unsigned)f2b(v.z) | ((unsigned)f2b(v.w) << 16);
        ((uint2*)Win)[i] = p;
    }
}

// ---------------------------------------------------------------------------
// Weff[e][c] = sum_d w_down[e*192+d][c] * rw[d]   (all f32, exact fold)
// ---------------------------------------------------------------------------
__global__ __launch_bounds__(256)
void weff_kernel(const float* __restrict__ wdn, const float* __restrict__ rw,
                 float* __restrict__ Weff)
{
    const int idx = blockIdx.x * 256 + threadIdx.x;
    const int e = idx / DIM, c = idx % DIM;
    float s = 0.0f;
    for (int d = 0; d < DLOW; d++)
        s += wdn[(size_t)(e * DLOW + d) * DIM + c] * rw[d];
    Weff[idx] = s;
}

// ---------------------------------------------------------------------------
// Router (all f32): thread t owns one token. logits -> softmax -> top2 -> aux
// ---------------------------------------------------------------------------
__global__ __launch_bounds__(256)
void router_kernel(const float* __restrict__ x, const float* __restrict__ Weff,
                   int* __restrict__ tokE, float* __restrict__ tokW,
                   float* __restrict__ accbuf)
{
    __shared__ float sW[NEXP * DIM];
    __shared__ float sAcc[16];
    const int tid = threadIdx.x;
    for (int i = tid; i < NEXP * DIM; i += 256) sW[i] = Weff[i];
    if (tid < 16) sAcc[tid] = 0.0f;
    __syncthreads();

    const int t = blockIdx.x * 256 + tid;
    const int b = t >> 10, n = t & 1023;
    const float* xb = x + (size_t)b * DIM * NPB + n;

    float lg[8];
#pragma unroll
    for (int e = 0; e < 8; e++) lg[e] = 0.0f;
    for (int c = 0; c < DIM; c++) {
        const float xv = xb[(size_t)c * NPB];
#pragma unroll
        for (int e = 0; e < 8; e++) lg[e] += xv * sW[e * DIM + c];
    }

    float mx = lg[0];
#pragma unroll
    for (int e = 1; e < 8; e++) mx = fmaxf(mx, lg[e]);
    float pr[8], s = 0.0f;
#pragma unroll
    for (int e = 0; e < 8; e++) { pr[e] = expf(lg[e] - mx); s += pr[e]; }
    const float inv = 1.0f / s;
#pragma unroll
    for (int e = 0; e < 8; e++) pr[e] *= inv;
    int e0 = 0;
#pragma unroll
    for (int e = 1; e < 8; e++) if (pr[e] > pr[e0]) e0 = e;
    int e1 = (e0 == 0) ? 1 : 0;
#pragma unroll
    for (int e = 0; e < 8; e++) if (e != e0 && pr[e] > pr[e1]) e1 = e;
    const float wsum = pr[e0] + pr[e1];
    tokE[2 * t + 0] = e0;  tokE[2 * t + 1] = e1;
    tokW[2 * t + 0] = pr[e0] / wsum;  tokW[2 * t + 1] = pr[e1] / wsum;

#pragma unroll
    for (int e = 0; e < 8; e++) atomicAdd(&sAcc[e], pr[e]);
    atomicAdd(&sAcc[8 + e0], 1.0f);
    atomicAdd(&sAcc[8 + e1], 1.0f);
    __syncthreads();
    if (tid < 16) atomicAdd(&accbuf[tid], sAcc[tid]);
}

// ---------------------------------------------------------------------------
extern "C" void kernel_launch(void* const* d_in, const int* in_sizes, int n_in,
                              void* d_out, int out_size, void* d_ws, size_t ws_size,
                              hipStream_t stream)
{
    (void)in_sizes; (void)n_in; (void)out_size;

    const float* x   = (const float*)d_in[0];
    const float* w1  = (const float*)d_in[1];
    const float* b1  = (const float*)d_in[2];
    const float* w2  = (const float*)d_in[3];
    const float* b2  = (const float*)d_in[4];
    const float* wdn = (const float*)d_in[5];
    const float* rw  = (const float*)d_in[6];
    const float* wup = (const float*)d_in[7];
    float* out = (float*)d_out;

    char* ws = (char*)d_ws;
    size_t off = 0;
    ushort_t* XTbf = (ushort_t*)(ws + off); off += (size_t)NTOK * DIM * 2;   // 12.6 MB
    ushort_t* Win  = (ushort_t*)(ws + off); off += (size_t)KCAT * DIM * 2;   //  7.1 MB
    ushort_t* Wcat = (ushort_t*)(ws + off); off += (size_t)DIM * KCAT * 2;   //  7.1 MB
    float*    Weff = (float*)  (ws + off);  off += (size_t)NEXP * DIM * 4;
    int*      tokE = (int*)    (ws + off);  off += (size_t)NTOK * 2 * 4;
    float*    tokW = (float*)  (ws + off);  off += (size_t)NTOK * 2 * 4;
    float*    accb = (float*)  (ws + off);  off += 256;

    // largest token-chunk that fits (graph-safe: pure function of ws_size)
    int chunk = NTOK / 4;
    if      (ws_size >= off + (size_t)NTOK * KCAT * 2)       chunk = NTOK;
    else if (ws_size >= off + (size_t)(NTOK / 2) * KCAT * 2) chunk = NTOK / 2;
    ushort_t* HU = (ushort_t*)(ws + off);                    // chunk*KCAT bf16

    const dim3 tb(32, 8);
    transpose_x_cvt  <<<dim3(32, 24, 8), tb, 0, stream>>>(x, XTbf);
    transpose_wup_cat<<<dim3(24, 48),    tb, 0, stream>>>(wup, Wcat);
    cvt_weights<<<NB_W2 + NB_WIN, 256, 0, stream>>>(w2, w1, wdn, Wcat, Win);
    weff_kernel<<<NEXP * DIM / 256, 256, 0, stream>>>(wdn, rw, Weff);

    hipMemsetAsync(accb, 0, 64, stream);
    router_kernel<<<NTOK / 256, 256, 0, stream>>>(x, Weff, tokE, tokW, accb);

    for (int c = 0; c < NTOK / chunk; c++) {
        const ushort_t* Ax = XTbf + (size_t)c * chunk * DIM;
        const int m_base = c * chunk;
        // HU = [gelu(XT@w1^T + b1) | gelu(XT@wdn^T) * routing weight]
        gemm_in<<<dim3(KCAT / 128, chunk / 256), 512, 0, stream>>>(
            Ax, Win, HU, b1, tokE, tokW, accb, out + (size_t)NTOK * DIM, m_base);
        // out = HU @ Wcat^T + b2 + x
        gemm_out<<<dim3(DIM / 128, chunk / 64), 256, 0, stream>>>(
            HU, Wcat, out, b2, x, m_base);
    }
}